// Round 15
// baseline (177.348 us; speedup 1.0000x reference)
//
#include <hip/hip_runtime.h>

#define HID    100
#define INP    4
#define TMAX   256
#define SB     16     // sequences per block = full MFMA M/N
#define ULD    136    // u_lds row stride in halves (272 B, 16B-aligned)
#define NTH    1024   // 16 waves -> 4 waves/SIMD
#define NTILES 25

typedef _Float16 half8 __attribute__((ext_vector_type(8)));
typedef float    f32x4 __attribute__((ext_vector_type(4)));

#define L2E  1.442695040888963f
#define L2E2 2.885390081777927f

__device__ __forceinline__ float fexp2(float x) { return __builtin_amdgcn_exp2f(x); }
__device__ __forceinline__ float frcp(float x)  { return __builtin_amdgcn_rcpf(x); }

__global__ __launch_bounds__(NTH) void lstm_persist(
    const float* __restrict__ xg,     // [N][T][4]
    const float* __restrict__ w_ih,   // [400][4]
    const float* __restrict__ w_hh,   // [400][100]
    const float* __restrict__ b_ih,   // [400]
    const float* __restrict__ b_hh,   // [400]
    const int*   __restrict__ lens,   // [N]
    float* __restrict__ out)          // [N][100]
{
    __shared__ _Float16 u_lds[2][SB * ULD];   // dbuf [seq][136]: h[0..99] | x[100..103] | 1 | 0-pad
    __shared__ int len_s[SB];
    __shared__ int maxlen_s;

    const int tid  = threadIdx.x;
    const int wave = tid >> 6;
    const int lane = tid & 63;
    const int l15  = lane & 15;    // seq (B-col = D-col)
    const int l4   = lane >> 4;
    const int seq0 = blockIdx.x * SB;

    if (tid < SB) len_s[tid] = lens[seq0 + tid];
    {   // zero both buffers; bias column (k==104) = 1.0
        _Float16* u0 = &u_lds[0][0];
        for (int i = tid; i < 2 * SB * ULD; i += NTH) {
            int col = i % ULD;
            u0[i] = (col == (HID + INP)) ? (_Float16)1.f : (_Float16)0.f;
        }
    }

    // ---- Weights as A-operand fragments, register-resident, PRESCALED.
    // Wave w owns tile w (and w+16 if < 25).
    // Position p = n*16 + l15: ty = l15&3 (i,f,g,o), unit = 25*(l15>>2) + n.
    // Row scale folded in: i,f,o -> -log2(e); g -> +2*log2(e).
    half8 afrag[2][4];
    int   tn[2];
    tn[0] = wave;
    tn[1] = (wave + 16 < NTILES) ? wave + 16 : NTILES;
    #pragma unroll
    for (int i = 0; i < 2; ++i) {
        int n = tn[i];
        if (n < NTILES) {
            int ty   = l15 & 3;
            int unit = 25 * (l15 >> 2) + n;
            int grow = ty * HID + unit;
            float scale = (ty == 2) ? L2E2 : -L2E;
            #pragma unroll
            for (int c = 0; c < 4; ++c) {
                half8 v;
                #pragma unroll
                for (int j = 0; j < 8; ++j) {
                    int k = c * 32 + l4 * 8 + j;
                    float w;
                    if (k < HID)             w = w_hh[grow * HID + k];
                    else if (k < HID + INP)  w = w_ih[grow * INP + (k - HID)];
                    else if (k == HID + INP) w = b_ih[grow] + b_hh[grow];
                    else                     w = 0.f;
                    v[j] = (_Float16)(scale * w);
                }
                afrag[i][c] = v;
            }
        }
    }

    __syncthreads();
    if (tid == 0) {
        int m = 0;
        for (int s = 0; s < SB; ++s) m = m > len_s[s] ? m : len_s[s];
        maxlen_s = m;
    }

    // x(0) into buf0; register-prefetch x(1), x(2). Wave 15 does x-duty.
    float xv1 = 0.f, xv2 = 0.f;
    const float* xs = nullptr;
    if (tid >= NTH - 64) {
        int idx = tid - (NTH - 64);
        int s = idx >> 2, ch = idx & 3;
        xs = xg + (size_t)(seq0 + s) * TMAX * INP + ch;
        u_lds[0][s * ULD + HID + ch] = (_Float16)xs[0];
        xv1 = xs[INP];
        xv2 = xs[2 * INP];
    }
    float creg[2] = {};
    __syncthreads();

    if (wave & 1) __builtin_amdgcn_s_setprio(1);   // static split (R10)
    const bool stagger = (wave & 1);

    const int maxlen = maxlen_s;
    const int mylen  = len_s[l15];
    const _Float16* ub0 = &u_lds[0][l15 * ULD + l4 * 8];
    const _Float16* ub1 = &u_lds[1][l15 * ULD + l4 * 8];

    for (int t = 0; t < maxlen; ++t) {
        const _Float16* ub = (t & 1) ? ub1 : ub0;
        _Float16* ubn = (t & 1) ? &u_lds[0][0] : &u_lds[1][0];

        // STAGGERED ENQUEUE: odd waves delay their LDS reads ~128 cy so even
        // waves' burst is serviced first and computes while odd reads drain.
        if (stagger) __builtin_amdgcn_s_sleep(2);
        __builtin_amdgcn_sched_barrier(0);   // pin: reads stay after the sleep

        // B-fragments: u for this step (col = l15 = seq, k = c*32 + l4*8 + j)
        half8 bfr[4];
        #pragma unroll
        for (int c = 0; c < 4; ++c)
            bfr[c] = *(const half8*)(ub + c * 32);

        // stage x(t+1) into next buffer; issue load of x(t+3)
        if (tid >= NTH - 64) {
            int idx = tid - (NTH - 64);
            int s = idx >> 2, ch = idx & 3;
            ubn[s * ULD + HID + ch] = (_Float16)xv1;
            xv1 = xv2;
            int tt = t + 3;
            xv2 = (tt < TMAX) ? xs[(size_t)tt * INP] : 0.f;
        }

        #pragma unroll
        for (int i = 0; i < 2; ++i) {
            if (tn[i] < NTILES) {
                f32x4 acc = {0.f, 0.f, 0.f, 0.f};
                #pragma unroll
                for (int c = 0; c < 4; ++c)
                    acc = __builtin_amdgcn_mfma_f32_16x16x32_f16(afrag[i][c], bfr[c], acc, 0, 0, 0);
                // acc[r] = prescaled preactivation; r: 0=i 1=f 2=g 3=o
                // lane (l15,l4): seq = l15, unit = 25*l4 + tn[i]
                // single-rcp c-update: cn = (c*A + P) * rcp(A*df)
                //   A = (1+e_i)(1+e_g), P = (e_g-1)(1+e_f), df = 1+e_f
                if (t < mylen) {
                    float e_i = fexp2(acc[0]);                    // exp(-z_i)
                    float e_f = fexp2(acc[1]);                    // exp(-z_f)
                    float e_g = fexp2(acc[2]);                    // exp(+2 z_g)
                    float e_o = fexp2(acc[3]);                    // exp(-z_o)
                    float tg  = 1.f + e_g;
                    float df  = 1.f + e_f;
                    float A   = __builtin_fmaf(e_i, tg, tg);      // (1+e_i)(1+e_g)
                    float P   = __builtin_fmaf(e_g, df, -df);     // (e_g-1)(1+e_f)
                    float num = __builtin_fmaf(creg[i], A, P);
                    float cn  = num * frcp(A * df);
                    float e_c = fexp2(fminf(L2E2 * cn, 60.f));    // exp(+2 cn), clamped
                    float t3  = 1.f + e_c;
                    float d3  = __builtin_fmaf(e_o, t3, t3);      // (1+e_o)(1+e_c)
                    float r3  = frcp(d3);
                    float hn  = __builtin_fmaf(e_c, r3, -r3);     // o*tanh(cn)
                    creg[i] = cn;
                    int unit = 25 * l4 + tn[i];
                    ubn[l15 * ULD + unit] = (_Float16)hn;
                    if (t == mylen - 1)
                        out[(size_t)(seq0 + l15) * HID + unit] = hn;
                }
            }
        }
        // lgkm-only drain (R9): LDS writes visible; global x-load stays in flight
        asm volatile("s_waitcnt lgkmcnt(0)" ::: "memory");
        __builtin_amdgcn_s_barrier();
    }
}

extern "C" void kernel_launch(void* const* d_in, const int* in_sizes, int n_in,
                              void* d_out, int out_size, void* d_ws, size_t ws_size,
                              hipStream_t stream) {
    const float* xg   = (const float*)d_in[0];
    const float* w_ih = (const float*)d_in[1];
    const float* w_hh = (const float*)d_in[2];
    const float* b_ih = (const float*)d_in[3];
    const float* b_hh = (const float*)d_in[4];
    const int*   lens = (const int*)d_in[5];
    float* out = (float*)d_out;
    const int N = in_sizes[5];           // 4096
    lstm_persist<<<dim3(N / SB), NTH, 0, stream>>>(xg, w_ih, w_hh, b_ih, b_hh, lens, out);
}

// Round 16
// 162.745 us; speedup vs baseline: 1.0897x; 1.0897x over previous
//
#include <hip/hip_runtime.h>

#define HID    100
#define INP    4
#define TMAX   256
#define SB     16     // sequences per block = full MFMA M/N
#define ULD    136    // u_lds row stride in halves (272 B, 16B-aligned)
#define NTH    1024   // 16 waves -> 4 waves/SIMD
#define NTILES 25

typedef _Float16 half8 __attribute__((ext_vector_type(8)));
typedef float    f32x4 __attribute__((ext_vector_type(4)));

#define L2E  1.442695040888963f
#define L2E2 2.885390081777927f

__device__ __forceinline__ float fexp2(float x) { return __builtin_amdgcn_exp2f(x); }
__device__ __forceinline__ float frcp(float x)  { return __builtin_amdgcn_rcpf(x); }

__global__ __launch_bounds__(NTH) void lstm_persist(
    const float* __restrict__ xg,     // [N][T][4]
    const float* __restrict__ w_ih,   // [400][4]
    const float* __restrict__ w_hh,   // [400][100]
    const float* __restrict__ b_ih,   // [400]
    const float* __restrict__ b_hh,   // [400]
    const int*   __restrict__ lens,   // [N]
    float* __restrict__ out)          // [N][100]
{
    __shared__ _Float16 u_lds[2][SB * ULD];   // dbuf [seq][136]: h[0..99] | x[100..103] | 1 | 0-pad
    __shared__ int len_s[SB];
    __shared__ int maxlen_s;

    const int tid  = threadIdx.x;
    const int wave = tid >> 6;
    const int lane = tid & 63;
    const int l15  = lane & 15;    // seq (B-col = D-col)
    const int l4   = lane >> 4;
    const int seq0 = blockIdx.x * SB;

    if (tid < SB) len_s[tid] = lens[seq0 + tid];
    {   // zero both buffers; bias column (k==104) = 1.0
        _Float16* u0 = &u_lds[0][0];
        for (int i = tid; i < 2 * SB * ULD; i += NTH) {
            int col = i % ULD;
            u0[i] = (col == (HID + INP)) ? (_Float16)1.f : (_Float16)0.f;
        }
    }

    // ---- Weights as A-operand fragments, register-resident, PRESCALED.
    // Wave w owns tile w (and w+16 if < 25).
    // Position p = n*16 + l15: ty = l15&3 (i,f,g,o), unit = 25*(l15>>2) + n.
    // Row scale folded in: i,f,o -> -log2(e); g -> +2*log2(e).
    half8 afrag[2][4];
    int   tn[2];
    tn[0] = wave;
    tn[1] = (wave + 16 < NTILES) ? wave + 16 : NTILES;
    #pragma unroll
    for (int i = 0; i < 2; ++i) {
        int n = tn[i];
        if (n < NTILES) {
            int ty   = l15 & 3;
            int unit = 25 * (l15 >> 2) + n;
            int grow = ty * HID + unit;
            float scale = (ty == 2) ? L2E2 : -L2E;
            #pragma unroll
            for (int c = 0; c < 4; ++c) {
                half8 v;
                #pragma unroll
                for (int j = 0; j < 8; ++j) {
                    int k = c * 32 + l4 * 8 + j;
                    float w;
                    if (k < HID)             w = w_hh[grow * HID + k];
                    else if (k < HID + INP)  w = w_ih[grow * INP + (k - HID)];
                    else if (k == HID + INP) w = b_ih[grow] + b_hh[grow];
                    else                     w = 0.f;
                    v[j] = (_Float16)(scale * w);
                }
                afrag[i][c] = v;
            }
        }
    }

    __syncthreads();
    if (tid == 0) {
        int m = 0;
        for (int s = 0; s < SB; ++s) m = m > len_s[s] ? m : len_s[s];
        maxlen_s = m;
    }

    // x(0) into buf0; register-prefetch x(1), x(2). Wave 15 does x-duty.
    float xv1 = 0.f, xv2 = 0.f;
    const float* xs = nullptr;
    if (tid >= NTH - 64) {
        int idx = tid - (NTH - 64);
        int s = idx >> 2, ch = idx & 3;
        xs = xg + (size_t)(seq0 + s) * TMAX * INP + ch;
        u_lds[0][s * ULD + HID + ch] = (_Float16)xs[0];
        xv1 = xs[INP];
        xv2 = xs[2 * INP];
    }
    float creg[2] = {};
    __syncthreads();

    if (wave & 1) __builtin_amdgcn_s_setprio(1);   // static split (R10)

    const int maxlen = maxlen_s;
    const int mylen  = len_s[l15];
    const _Float16* ub0 = &u_lds[0][l15 * ULD + l4 * 8];
    const _Float16* ub1 = &u_lds[1][l15 * ULD + l4 * 8];

    for (int t = 0; t < maxlen; ++t) {
        const _Float16* ub = (t & 1) ? ub1 : ub0;
        _Float16* ubn = (t & 1) ? &u_lds[0][0] : &u_lds[1][0];

        // B-fragments: u for this step (col = l15 = seq, k = c*32 + l4*8 + j)
        half8 bfr[4];
        #pragma unroll
        for (int c = 0; c < 4; ++c)
            bfr[c] = *(const half8*)(ub + c * 32);

        // stage x(t+1) into next buffer; issue load of x(t+3)
        if (tid >= NTH - 64) {
            int idx = tid - (NTH - 64);
            int s = idx >> 2, ch = idx & 3;
            ubn[s * ULD + HID + ch] = (_Float16)xv1;
            xv1 = xv2;
            int tt = t + 3;
            xv2 = (tt < TMAX) ? xs[(size_t)tt * INP] : 0.f;
        }

        #pragma unroll
        for (int i = 0; i < 2; ++i) {
            if (tn[i] < NTILES) {
                f32x4 acc = {0.f, 0.f, 0.f, 0.f};
                #pragma unroll
                for (int c = 0; c < 4; ++c)
                    acc = __builtin_amdgcn_mfma_f32_16x16x32_f16(afrag[i][c], bfr[c], acc, 0, 0, 0);
                // acc[r] = prescaled preactivation; r: 0=i 1=f 2=g 3=o
                // lane (l15,l4): seq = l15, unit = 25*l4 + tn[i]
                // single-rcp c-update: cn = (c*A + P) * rcp(A*df)
                //   A = (1+e_i)(1+e_g), P = (e_g-1)(1+e_f), df = 1+e_f
                if (t < mylen) {
                    float e_i = fexp2(acc[0]);                    // exp(-z_i)
                    float e_f = fexp2(acc[1]);                    // exp(-z_f)
                    float e_g = fexp2(acc[2]);                    // exp(+2 z_g)
                    float e_o = fexp2(acc[3]);                    // exp(-z_o)
                    float tg  = 1.f + e_g;
                    float df  = 1.f + e_f;
                    float A   = __builtin_fmaf(e_i, tg, tg);      // (1+e_i)(1+e_g)
                    float P   = __builtin_fmaf(e_g, df, -df);     // (e_g-1)(1+e_f)
                    float num = __builtin_fmaf(creg[i], A, P);
                    float cn  = num * frcp(A * df);
                    float e_c = fexp2(fminf(L2E2 * cn, 60.f));    // exp(+2 cn), clamped
                    float t3  = 1.f + e_c;
                    float d3  = __builtin_fmaf(e_o, t3, t3);      // (1+e_o)(1+e_c)
                    float r3  = frcp(d3);
                    float hn  = __builtin_fmaf(e_c, r3, -r3);     // o*tanh(cn)
                    creg[i] = cn;
                    int unit = 25 * l4 + tn[i];
                    ubn[l15 * ULD + unit] = (_Float16)hn;
                    if (t == mylen - 1)
                        out[(size_t)(seq0 + l15) * HID + unit] = hn;
                }
            }
        }
        // lgkm-only drain (R9): LDS writes visible; global x-load stays in flight
        asm volatile("s_waitcnt lgkmcnt(0)" ::: "memory");
        __builtin_amdgcn_s_barrier();
    }
}

extern "C" void kernel_launch(void* const* d_in, const int* in_sizes, int n_in,
                              void* d_out, int out_size, void* d_ws, size_t ws_size,
                              hipStream_t stream) {
    const float* xg   = (const float*)d_in[0];
    const float* w_ih = (const float*)d_in[1];
    const float* w_hh = (const float*)d_in[2];
    const float* b_ih = (const float*)d_in[3];
    const float* b_hh = (const float*)d_in[4];
    const int*   lens = (const int*)d_in[5];
    float* out = (float*)d_out;
    const int N = in_sizes[5];           // 4096
    lstm_persist<<<dim3(N / SB), NTH, 0, stream>>>(xg, w_ih, w_hh, b_ih, b_hh, lens, out);
}